// Round 13
// baseline (1019.046 us; speedup 1.0000x reference)
//
#include <hip/hip_runtime.h>

// Sizes (fixed for this problem)
#define T_TOK 1024
#define H_DIM 2048
#define E_NUM 32
#define I_DIM 1024
#define IS_DIM 2048

typedef float  f32x4 __attribute__((ext_vector_type(4)));
typedef short  s16x8 __attribute__((ext_vector_type(8)));
typedef unsigned short u16x8 __attribute__((ext_vector_type(8)));

__device__ __forceinline__ unsigned short f2bf(float f) {
    unsigned u = __builtin_bit_cast(unsigned, f);
    u = (u + 0x7fffu + ((u >> 16) & 1u)) >> 16;
    return (unsigned short)u;
}
__device__ __forceinline__ float bf2f(unsigned short h) {
    return __builtin_bit_cast(float, (unsigned)h << 16);
}

// LDS tiles are [rows][32 k-elems] bf16 (64 B/row). 16-B chunk index XORed
// with low row bits -> strided row reads spread over banks (<=4-way, m136:
// 1.58x — LDS far from critical path). 16-B alignment preserved.
__device__ __forceinline__ int swzL(int r, int kchunk) {
    return r * 32 + ((kchunk ^ (r & 3)) << 3);
}

// ---------------------------------------------------------------------------
// x (fp32) -> bf16 once; all GEMM A-operands are bf16.
// ---------------------------------------------------------------------------
__global__ __launch_bounds__(256) void cvt_k(
    const float* __restrict__ x, unsigned short* __restrict__ xb)
{
    const int i = (blockIdx.x * 256 + threadIdx.x) * 8;
    f32x4 a = *(const f32x4*)(x + i);
    f32x4 b = *(const f32x4*)(x + i + 4);
    u16x8 h = { f2bf(a[0]), f2bf(a[1]), f2bf(a[2]), f2bf(a[3]),
                f2bf(b[0]), f2bf(b[1]), f2bf(b[2]), f2bf(b[3]) };
    *(u16x8*)(xb + i) = h;
}

// ---------------------------------------------------------------------------
// silu(g)*u elementwise, bf16 in / bf16 out (out aliases g).
// ---------------------------------------------------------------------------
__global__ __launch_bounds__(256) void silu_k(
    const unsigned short* __restrict__ g, const unsigned short* __restrict__ u,
    unsigned short* __restrict__ o)
{
    const int i = (blockIdx.x * 256 + threadIdx.x) * 8;
    u16x8 gv = *(const u16x8*)(g + i);
    u16x8 uv = *(const u16x8*)(u + i);
    u16x8 r;
    #pragma unroll
    for (int j = 0; j < 8; ++j) {
        float gf = bf2f(gv[j]);
        float uf = bf2f(uv[j]);
        r[j] = f2bf(gf / (1.f + expf(-gf)) * uf);
    }
    *(u16x8*)(o + i) = r;
}

// ---------------------------------------------------------------------------
// Routing: 4 tokens per 256-thread block, one wave per token.
// ---------------------------------------------------------------------------
__global__ __launch_bounds__(256) void route_k(
    const float* __restrict__ x, const float* __restrict__ gw,
    const float* __restrict__ bias, int* __restrict__ tidx,
    float* __restrict__ tw)
{
    const int w = threadIdx.x >> 6;
    const int lane = threadIdx.x & 63;
    const int t = blockIdx.x * 4 + w;
    __shared__ float xs[4][H_DIM];
    __shared__ float sfc[4][E_NUM];
    __shared__ float sc[4][E_NUM];

    for (int i = threadIdx.x; i < 4 * (H_DIM / 4); i += 256) {
        int tt = i >> 9;
        int c = i & 511;
        *(f32x4*)&xs[tt][c * 4] =
            *(const f32x4*)(x + (size_t)(blockIdx.x * 4 + tt) * H_DIM + c * 4);
    }
    __syncthreads();

    const int eq = (lane & 7) * 4;
    const int hs = lane >> 3;
    f32x4 acc = {0.f, 0.f, 0.f, 0.f};
    #pragma unroll 4
    for (int h = hs; h < H_DIM; h += 8) {
        float xv = xs[w][h];
        f32x4 gv = *(const f32x4*)(gw + (size_t)h * E_NUM + eq);
        acc += gv * xv;
    }
    #pragma unroll
    for (int m = 8; m < 64; m <<= 1) {
        acc[0] += __shfl_xor(acc[0], m);
        acc[1] += __shfl_xor(acc[1], m);
        acc[2] += __shfl_xor(acc[2], m);
        acc[3] += __shfl_xor(acc[3], m);
    }
    if (lane < 8) {
        #pragma unroll
        for (int j = 0; j < 4; ++j) {
            float s = 1.f / (1.f + expf(-acc[j]));
            sc[w][eq + j] = s;
            sfc[w][eq + j] = s + bias[eq + j];
        }
    }
    __syncthreads();

    if (lane == 0) {
        float gs[4];
        for (int gg = 0; gg < 4; ++gg) {
            float m1 = -1e30f, m2 = -1e30f;
            for (int j = 0; j < 8; ++j) {
                float v = sfc[w][gg * 8 + j];
                if (v > m1) { m2 = m1; m1 = v; }
                else if (v > m2) { m2 = v; }
            }
            gs[gg] = m1 + m2;
        }
        int g1 = 0;
        for (int gg = 1; gg < 4; ++gg) if (gs[gg] > gs[g1]) g1 = gg;
        int g2 = (g1 == 0) ? 1 : 0;
        for (int gg = 0; gg < 4; ++gg)
            if (gg != g1 && gs[gg] > gs[g2]) g2 = gg;

        unsigned allow = (0xFFu << (g1 * 8)) | (0xFFu << (g2 * 8));
        unsigned taken = 0u;
        int   isel[8];
        float wsel[8];
        float wsum = 0.f;
        for (int k = 0; k < 8; ++k) {
            int best = 0; float bv = -1e30f;
            for (int e2 = 0; e2 < 32; ++e2) {
                if (((allow >> e2) & 1u) && !((taken >> e2) & 1u)) {
                    float v = sfc[w][e2];
                    if (v > bv) { bv = v; best = e2; }
                }
            }
            taken |= 1u << best;
            isel[k] = best;
            wsel[k] = sc[w][best];
            wsum += sc[w][best];
        }
        const float f = 2.5f / wsum;
        for (int k = 0; k < 8; ++k) {
            tidx[t * 8 + k] = isel[k];
            tw[t * 8 + k] = wsel[k] * f;
        }
    }
}

// ---------------------------------------------------------------------------
// Build per-expert token lists; record token's position in its expert list.
// ---------------------------------------------------------------------------
__global__ __launch_bounds__(64) void build_k(
    const int* __restrict__ tidx, int* __restrict__ ltok,
    int* __restrict__ ppos, int* __restrict__ counts)
{
    const int e = blockIdx.x;
    const int lane = threadIdx.x;
    int cnt = 0;
    for (int t0 = 0; t0 < T_TOK; t0 += 64) {
        const int t = t0 + lane;
        int sel = 0, kk = 0;
        #pragma unroll
        for (int k = 0; k < 8; ++k) {
            if (tidx[t * 8 + k] == e) { sel = 1; kk = k; }
        }
        unsigned long long m = __ballot(sel);
        int pos = __popcll(m & ((1ull << lane) - 1ull));
        if (sel) {
            ltok[e * T_TOK + cnt + pos] = t;
            ppos[t * 8 + kk] = cnt + pos;
        }
        cnt += __popcll(m);
    }
    if (lane == 0) counts[e] = cnt;
}

__global__ void prefix_k(const int* __restrict__ counts, int* __restrict__ offsets)
{
    if (threadIdx.x == 0) {
        int off = 0;
        for (int e = 0; e < E_NUM; ++e) { offsets[e] = off; off += counts[e]; }
    }
}

// ---------------------------------------------------------------------------
// Combine: out[t] = shd[t] + sum_k tw[t,k] * yd[offsets[e_k] + ppos[t,k]].
// ---------------------------------------------------------------------------
__global__ __launch_bounds__(256) void combine_k(
    const int* __restrict__ tidx, const float* __restrict__ tw,
    const int* __restrict__ offsets, const int* __restrict__ ppos,
    const unsigned short* __restrict__ shd, const unsigned short* __restrict__ yd,
    float* __restrict__ out)
{
    const int t = blockIdx.x;
    const int h = threadIdx.x * 8;
    u16x8 sv = *(const u16x8*)(shd + (size_t)t * H_DIM + h);
    float a[8];
    #pragma unroll
    for (int j = 0; j < 8; ++j) a[j] = bf2f(sv[j]);
    #pragma unroll
    for (int k = 0; k < 8; ++k) {
        int e = tidx[t * 8 + k];
        float w = tw[t * 8 + k];
        size_t row = (size_t)(offsets[e] + ppos[t * 8 + k]);
        u16x8 v = *(const u16x8*)(yd + row * H_DIM + h);
        #pragma unroll
        for (int j = 0; j < 8; ++j) a[j] += w * bf2f(v[j]);
    }
    f32x4 lo = { a[0], a[1], a[2], a[3] };
    f32x4 hi = { a[4], a[5], a[6], a[7] };
    *(f32x4*)(out + (size_t)t * H_DIM + h)     = lo;
    *(f32x4*)(out + (size_t)t * H_DIM + h + 4) = hi;
}

// ---------------------------------------------------------------------------
// GEMM: 320x32 tile, BK=32, 320 threads (5 waves, each one 64-row strip;
// FM=4, FN=2). A AND B staged in swizzled double-buffered LDS; depth-2 X/Y
// register pipeline (R8-proven). VGPR budget ~120 -> 16 waves/CU; LDS 44 KB
// -> 3 blocks/CU resident: cross-block TLP hides the per-iter barrier drain.
// Routed: grid.x=1, BM=320 >= counts[e] -> weight panels streamed once.
// MSPLIT: y-grid doubled, second half = (B2g, out2). Output bf16.
// ---------------------------------------------------------------------------
template<int MSPLIT, int EXPERT, int GATHER>
__global__ __launch_bounds__(320, 4) void gemm_k(
    const unsigned short* __restrict__ A,
    const float* __restrict__ B1g, const float* __restrict__ B2g,
    unsigned short* __restrict__ out1, unsigned short* __restrict__ out2,
    const int* __restrict__ counts, const int* __restrict__ offsets,
    const int* __restrict__ ltok,
    int M, int N, int K)
{
    constexpr int BM = 320;

    const int e = blockIdx.z;
    const int Mloc = EXPERT ? counts[e] : M;
    const int rb = EXPERT ? offsets[e] : 0;

    int ymat = 0, ypanel = blockIdx.y;
    if (MSPLIT) {
        const int half = gridDim.y >> 1;
        ymat = (blockIdx.y >= half) ? 1 : 0;
        ypanel -= ymat * half;
    }
    const float* B = ymat ? B2g : B1g;
    unsigned short* outp = ymat ? out2 : out1;
    if (EXPERT) B += (size_t)e * K * N;
    const int colB = ypanel * 32;

    __shared__ unsigned short lA[2][BM * 32];
    __shared__ unsigned short lB[2][32 * 32];

    const int tid = threadIdx.x;
    const int lane = tid & 63;
    const int wv = tid >> 6;           // 0..4 = 64-row M strip
    const int q = lane >> 4;           // k-chunk 0..3
    const int lr = lane & 15;

    // ---- B staging: threads 0..255, one f32x4 (4 n-cols of one k-row) ----
    const bool doB = tid < 256;
    const int nq = tid & 7;            // n-quad 0..7
    const int kr = (tid >> 3) & 31;    // k-row 0..31
    const float* bp = B + (size_t)kr * N + colB + nq * 4;

    f32x4 acc[4][2];
    u16x8 paX[4], paY[4];
    f32x4 pbX, pbY;
    const unsigned short* apb = nullptr;

    auto loadT = [&](int k0, u16x8 (&pa)[4], f32x4& pb) {
        #pragma unroll
        for (int i = 0; i < 4; ++i)
            pa[i] = *(const u16x8*)(apb + k0 + i * 8);
        if (doB) pb = *(const f32x4*)(bp + (size_t)k0 * N);
    };

    auto storeT = [&](int p, u16x8 (&pa)[4], f32x4& pb) {
        #pragma unroll
        for (int i = 0; i < 4; ++i)
            *(u16x8*)&lA[p][swzL(tid, i)] = pa[i];
        if (doB) {
            #pragma unroll
            for (int j = 0; j < 4; ++j) {
                int n = nq * 4 + j;
                lB[p][n * 32 + (((kr >> 3) ^ (n & 3)) << 3) + (kr & 7)] = f2bf(pb[j]);
            }
        }
    };

    auto compute = [&](int p) {
        s16x8 af[4], bf[2];
        #pragma unroll
        for (int fm = 0; fm < 4; ++fm) {
            int row = wv * 64 + fm * 16 + lr;
            af[fm] = *(const s16x8*)&lA[p][swzL(row, q)];
        }
        #pragma unroll
        for (int fn = 0; fn < 2; ++fn) {
            int n = fn * 16 + lr;
            bf[fn] = *(const s16x8*)&lB[p][n * 32 + ((q ^ (n & 3)) << 3)];
        }
        #pragma unroll
        for (int fm = 0; fm < 4; ++fm)
            #pragma unroll
            for (int fn = 0; fn < 2; ++fn)
                acc[fm][fn] = __builtin_amdgcn_mfma_f32_16x16x32_bf16(
                    af[fm], bf[fn], acc[fm][fn], 0, 0, 0);
    };

    const int nk = K >> 5;             // 32 or 64 (even)

    for (int row0 = blockIdx.x * BM; row0 < Mloc; row0 += gridDim.x * BM) {
        // A row pointer for this m-tile (one row per thread)
        {
            int rr = row0 + tid;
            if (rr >= Mloc) rr = Mloc - 1;
            int grow = GATHER ? ltok[e * T_TOK + rr] : (rb + rr);
            apb = A + (size_t)grow * K;
        }
        #pragma unroll
        for (int a = 0; a < 4; ++a)
            #pragma unroll
            for (int b = 0; b < 2; ++b)
                acc[a][b] = f32x4{0.f, 0.f, 0.f, 0.f};

        loadT(0, paX, pbX);
        loadT(32, paY, pbY);
        __syncthreads();               // prior m-tile done with LDS
        storeT(0, paX, pbX);
        __syncthreads();

        for (int kt = 0; kt < nk; kt += 2) {
            if (kt + 2 < nk) loadT((kt + 2) << 5, paX, pbX);
            compute(0);
            storeT(1, paY, pbY);       // counted vmcnt: newer loads in flight
            __syncthreads();
            if (kt + 3 < nk) loadT((kt + 3) << 5, paY, pbY);
            compute(1);
            if (kt + 2 < nk) {
                storeT(0, paX, pbX);
                __syncthreads();
            }
        }

        // ---- epilogue: bf16 store ----
        const int fr = q << 2;
        #pragma unroll
        for (int fm = 0; fm < 4; ++fm)
            #pragma unroll
            for (int fn = 0; fn < 2; ++fn)
                #pragma unroll
                for (int j = 0; j < 4; ++j) {
                    int r = wv * 64 + fm * 16 + fr + j;
                    if (row0 + r < Mloc) {
                        int cc = colB + fn * 16 + lr;
                        outp[(size_t)(rb + row0 + r) * N + cc] = f2bf(acc[fm][fn][j]);
                    }
                }
    }
}

// ---------------------------------------------------------------------------
extern "C" void kernel_launch(void* const* d_in, const int* in_sizes, int n_in,
                              void* d_out, int out_size, void* d_ws, size_t ws_size,
                              hipStream_t stream) {
    const float* x       = (const float*)d_in[0];
    const float* gate_w  = (const float*)d_in[1];
    const float* bias    = (const float*)d_in[2];
    const float* w_gate  = (const float*)d_in[3];
    const float* w_up    = (const float*)d_in[4];
    const float* w_down  = (const float*)d_in[5];
    const float* sw_gate = (const float*)d_in[6];
    const float* sw_up   = (const float*)d_in[7];
    const float* sw_down = (const float*)d_in[8];
    float* out = (float*)d_out;

    char* ws = (char*)d_ws;
    int*   topk_idx = (int*)ws;                        // 32 KB
    float* topk_w   = (float*)(ws + 32768);            // 32 KB
    int*   counts   = (int*)(ws + 65536);              // 128 B
    int*   offsets  = (int*)(ws + 65664);              // 128 B
    int*   ppos     = (int*)(ws + 65792);              // 32 KB
    int*   ltok     = (int*)(ws + 98560);              // 128 KB
    unsigned short* xbf = (unsigned short*)(ws + 262144);            // 4 MB
    unsigned short* g_s = xbf + (size_t)T_TOK * H_DIM;               // 4 MB
    unsigned short* u_s = g_s + (size_t)T_TOK * IS_DIM;              // 4 MB
    unsigned short* shd = u_s + (size_t)T_TOK * IS_DIM;              // 4 MB
    unsigned short* g_r = shd + (size_t)T_TOK * H_DIM;               // 16 MB
    unsigned short* u_r = g_r + (size_t)T_TOK * 8 * I_DIM;           // 16 MB
    unsigned short* yd  = u_r + (size_t)T_TOK * 8 * I_DIM;           // 32 MB

    cvt_k<<<T_TOK * H_DIM / 2048, 256, 0, stream>>>(x, xbf);
    route_k<<<T_TOK / 4, 256, 0, stream>>>(x, gate_w, bias, topk_idx, topk_w);
    build_k<<<E_NUM, 64, 0, stream>>>(topk_idx, ltok, ppos, counts);
    prefix_k<<<1, 64, 0, stream>>>(counts, offsets);

    // shared gate/up (y-split): y 0..63 -> gate, 64..127 -> up
    gemm_k<1,0,0><<<dim3(4, 128, 1), 320, 0, stream>>>(
        xbf, sw_gate, sw_up, g_s, u_s, nullptr, nullptr, nullptr,
        T_TOK, IS_DIM, H_DIM);
    silu_k<<<T_TOK * IS_DIM / 2048, 256, 0, stream>>>(g_s, u_s, g_s);

    // routed gate/up (y-split): BM=320 covers counts; weights streamed once
    gemm_k<1,1,1><<<dim3(1, 64, E_NUM), 320, 0, stream>>>(
        xbf, w_gate, w_up, g_r, u_r, counts, offsets, ltok,
        T_TOK, I_DIM, H_DIM);
    silu_k<<<T_TOK * 8 * I_DIM / 2048, 256, 0, stream>>>(g_r, u_r, g_r);

    // shared down -> shd (bf16)
    gemm_k<0,0,0><<<dim3(4, 64, 1), 320, 0, stream>>>(
        g_s, sw_down, nullptr, shd, nullptr, nullptr, nullptr, nullptr,
        T_TOK, H_DIM, IS_DIM);

    // routed down -> yd rows (bf16, no atomics)
    gemm_k<0,1,0><<<dim3(1, 64, E_NUM), 320, 0, stream>>>(
        g_r, w_down, nullptr, yd, nullptr, counts, offsets, ltok,
        T_TOK, H_DIM, I_DIM);

    // out[t] = shd[t] + sum_k w_k * yd[row_k]
    combine_k<<<T_TOK, 256, 0, stream>>>(
        topk_idx, topk_w, offsets, ppos, shd, yd, out);
}

// Round 14
// 1017.525 us; speedup vs baseline: 1.0015x; 1.0015x over previous
//
#include <hip/hip_runtime.h>

// Sizes (fixed for this problem)
#define T_TOK 1024
#define H_DIM 2048
#define E_NUM 32
#define I_DIM 1024
#define IS_DIM 2048

typedef float  f32x4 __attribute__((ext_vector_type(4)));
typedef short  s16x8 __attribute__((ext_vector_type(8)));
typedef unsigned short u16x4 __attribute__((ext_vector_type(4)));
typedef unsigned short u16x8 __attribute__((ext_vector_type(8)));

__device__ __forceinline__ unsigned short f2bf(float f) {
    unsigned u = __builtin_bit_cast(unsigned, f);
    u = (u + 0x7fffu + ((u >> 16) & 1u)) >> 16;
    return (unsigned short)u;
}
__device__ __forceinline__ float bf2f(unsigned short h) {
    return __builtin_bit_cast(float, (unsigned)h << 16);
}

// ---------------------------------------------------------------------------
// x (fp32) -> bf16 once; all GEMM A-operands are bf16.
// ---------------------------------------------------------------------------
__global__ __launch_bounds__(256) void cvt_k(
    const float* __restrict__ x, unsigned short* __restrict__ xb)
{
    const int i = (blockIdx.x * 256 + threadIdx.x) * 8;
    f32x4 a = *(const f32x4*)(x + i);
    f32x4 b = *(const f32x4*)(x + i + 4);
    u16x8 h = { f2bf(a[0]), f2bf(a[1]), f2bf(a[2]), f2bf(a[3]),
                f2bf(b[0]), f2bf(b[1]), f2bf(b[2]), f2bf(b[3]) };
    *(u16x8*)(xb + i) = h;
}

// ---------------------------------------------------------------------------
// Routing: 4 tokens per 256-thread block, one wave per token.
// ---------------------------------------------------------------------------
__global__ __launch_bounds__(256) void route_k(
    const float* __restrict__ x, const float* __restrict__ gw,
    const float* __restrict__ bias, int* __restrict__ tidx,
    float* __restrict__ tw)
{
    const int w = threadIdx.x >> 6;
    const int lane = threadIdx.x & 63;
    const int t = blockIdx.x * 4 + w;
    __shared__ float xs[4][H_DIM];
    __shared__ float sfc[4][E_NUM];
    __shared__ float sc[4][E_NUM];

    for (int i = threadIdx.x; i < 4 * (H_DIM / 4); i += 256) {
        int tt = i >> 9;
        int c = i & 511;
        *(f32x4*)&xs[tt][c * 4] =
            *(const f32x4*)(x + (size_t)(blockIdx.x * 4 + tt) * H_DIM + c * 4);
    }
    __syncthreads();

    const int eq = (lane & 7) * 4;
    const int hs = lane >> 3;
    f32x4 acc = {0.f, 0.f, 0.f, 0.f};
    #pragma unroll 4
    for (int h = hs; h < H_DIM; h += 8) {
        float xv = xs[w][h];
        f32x4 gv = *(const f32x4*)(gw + (size_t)h * E_NUM + eq);
        acc += gv * xv;
    }
    #pragma unroll
    for (int m = 8; m < 64; m <<= 1) {
        acc[0] += __shfl_xor(acc[0], m);
        acc[1] += __shfl_xor(acc[1], m);
        acc[2] += __shfl_xor(acc[2], m);
        acc[3] += __shfl_xor(acc[3], m);
    }
    if (lane < 8) {
        #pragma unroll
        for (int j = 0; j < 4; ++j) {
            float s = 1.f / (1.f + expf(-acc[j]));
            sc[w][eq + j] = s;
            sfc[w][eq + j] = s + bias[eq + j];
        }
    }
    __syncthreads();

    if (lane == 0) {
        float gs[4];
        for (int gg = 0; gg < 4; ++gg) {
            float m1 = -1e30f, m2 = -1e30f;
            for (int j = 0; j < 8; ++j) {
                float v = sfc[w][gg * 8 + j];
                if (v > m1) { m2 = m1; m1 = v; }
                else if (v > m2) { m2 = v; }
            }
            gs[gg] = m1 + m2;
        }
        int g1 = 0;
        for (int gg = 1; gg < 4; ++gg) if (gs[gg] > gs[g1]) g1 = gg;
        int g2 = (g1 == 0) ? 1 : 0;
        for (int gg = 0; gg < 4; ++gg)
            if (gg != g1 && gs[gg] > gs[g2]) g2 = gg;

        unsigned allow = (0xFFu << (g1 * 8)) | (0xFFu << (g2 * 8));
        unsigned taken = 0u;
        int   isel[8];
        float wsel[8];
        float wsum = 0.f;
        for (int k = 0; k < 8; ++k) {
            int best = 0; float bv = -1e30f;
            for (int e2 = 0; e2 < 32; ++e2) {
                if (((allow >> e2) & 1u) && !((taken >> e2) & 1u)) {
                    float v = sfc[w][e2];
                    if (v > bv) { bv = v; best = e2; }
                }
            }
            taken |= 1u << best;
            isel[k] = best;
            wsel[k] = sc[w][best];
            wsum += sc[w][best];
        }
        const float f = 2.5f / wsum;
        for (int k = 0; k < 8; ++k) {
            tidx[t * 8 + k] = isel[k];
            tw[t * 8 + k] = wsel[k] * f;
        }
    }
}

// ---------------------------------------------------------------------------
// Build per-expert token lists; record token's position in its expert list.
// ---------------------------------------------------------------------------
__global__ __launch_bounds__(64) void build_k(
    const int* __restrict__ tidx, int* __restrict__ ltok,
    int* __restrict__ ppos, int* __restrict__ counts)
{
    const int e = blockIdx.x;
    const int lane = threadIdx.x;
    int cnt = 0;
    for (int t0 = 0; t0 < T_TOK; t0 += 64) {
        const int t = t0 + lane;
        int sel = 0, kk = 0;
        #pragma unroll
        for (int k = 0; k < 8; ++k) {
            if (tidx[t * 8 + k] == e) { sel = 1; kk = k; }
        }
        unsigned long long m = __ballot(sel);
        int pos = __popcll(m & ((1ull << lane) - 1ull));
        if (sel) {
            ltok[e * T_TOK + cnt + pos] = t;
            ppos[t * 8 + kk] = cnt + pos;
        }
        cnt += __popcll(m);
    }
    if (lane == 0) counts[e] = cnt;
}

__global__ void prefix_k(const int* __restrict__ counts, int* __restrict__ offsets)
{
    if (threadIdx.x == 0) {
        int off = 0;
        for (int e = 0; e < E_NUM; ++e) { offsets[e] = off; off += counts[e]; }
    }
}

// ---------------------------------------------------------------------------
// Combine: out[t] = shd[t] + sum_k tw[t,k] * yd[offsets[e_k] + ppos[t,k]].
// ---------------------------------------------------------------------------
__global__ __launch_bounds__(256) void combine_k(
    const int* __restrict__ tidx, const float* __restrict__ tw,
    const int* __restrict__ offsets, const int* __restrict__ ppos,
    const unsigned short* __restrict__ shd, const unsigned short* __restrict__ yd,
    float* __restrict__ out)
{
    const int t = blockIdx.x;
    const int h = threadIdx.x * 8;
    u16x8 sv = *(const u16x8*)(shd + (size_t)t * H_DIM + h);
    float a[8];
    #pragma unroll
    for (int j = 0; j < 8; ++j) a[j] = bf2f(sv[j]);
    #pragma unroll
    for (int k = 0; k < 8; ++k) {
        int e = tidx[t * 8 + k];
        float w = tw[t * 8 + k];
        size_t row = (size_t)(offsets[e] + ppos[t * 8 + k]);
        u16x8 v = *(const u16x8*)(yd + row * H_DIM + h);
        #pragma unroll
        for (int j = 0; j < 8; ++j) a[j] += w * bf2f(v[j]);
    }
    f32x4 lo = { a[0], a[1], a[2], a[3] };
    f32x4 hi = { a[4], a[5], a[6], a[7] };
    *(f32x4*)(out + (size_t)t * H_DIM + h)     = lo;
    *(f32x4*)(out + (size_t)t * H_DIM + h + 4) = hi;
}

// ---------------------------------------------------------------------------
// GEMM: the Round-6 measured winner (716 us total), minimally modified.
// BMx64 tile, BK=32, 512 threads (8 waves, 4Mx2N), padded-40 LDS rows,
// depth-2 X/Y register pipeline. A is ALWAYS bf16 now (xbf or act buffers).
// DUAL:   gate+up in one block, SiLU fused, bf16 act store
// EXPERT: blockIdx.z = expert, M = counts[e]; B loads nontemporal
// GATHER: A rows via ltok
// Output: always bf16 at (rb+row)*N (combine_k builds the final fp32 out).
// ---------------------------------------------------------------------------
template<int DUAL, int EXPERT, int GATHER, int BM>
__global__ __launch_bounds__(512) void gemm_k(
    const unsigned short* __restrict__ A,
    const float* __restrict__ B1g, const float* __restrict__ B2g,
    unsigned short* __restrict__ outp,
    const int* __restrict__ counts, const int* __restrict__ offsets,
    const int* __restrict__ ltok,
    int M, int N, int K)
{
    constexpr int FM  = BM / 64;       // A frags per wave
    constexpr int WR  = BM / 4;        // rows per M-wave stripe
    constexpr int TPR = 512 / BM;      // threads per A row (2 or 4)
    constexpr int KSP = 32 / TPR;      // k elems per thread (16 or 8)
    constexpr int NB  = KSP / 8;       // u16x8 ops per thread (2 or 1)

    const int e = blockIdx.z;
    const int Mloc = EXPERT ? counts[e] : M;
    const int row0 = blockIdx.x * BM;
    if (row0 >= Mloc) return;
    const int col0 = blockIdx.y * 64;
    const int rb = EXPERT ? offsets[e] : 0;

    const float* B1 = B1g;
    const float* B2 = B2g;
    if (EXPERT) {
        size_t eo = (size_t)e * K * N;
        B1 += eo;
        if (DUAL) B2 += eo;
    }

    __shared__ unsigned short lA[2][BM][40];
    __shared__ unsigned short lB[2][DUAL + 1][64][40];

    const int tid = threadIdx.x;
    const int lane = tid & 63;
    const int wv = tid >> 6;
    const int wm = wv >> 1;            // 0..3
    const int wn = wv & 1;             // 0..1

    // ---- A staging pointer (bf16, one row-segment per thread) ----
    const int arow = tid / TPR;
    const int akb  = (tid % TPR) * KSP;
    const unsigned short* apb;
    {
        int rr = row0 + arow;
        if (rr >= Mloc) rr = Mloc - 1;
        int grow = GATHER ? ltok[e * T_TOK + rr] : (rb + rr);
        apb = A + (size_t)grow * K + akb;
    }

    // ---- B staging: 4k x 4n micro-tile per thread ----
    const bool doB = tid < (DUAL ? 256 : 128);
    const int bmat = DUAL ? (tid >> 7) : 0;
    const int t7 = tid & 127;
    const int nq = t7 & 15;            // n group of 4
    const int kq = t7 >> 4;            // k group of 4 (0..7)
    const float* bp = (bmat ? B2 : B1) + (size_t)(4 * kq) * N + col0 + nq * 4;

    f32x4 acc1[FM][2], acc2[FM][2];
    #pragma unroll
    for (int a = 0; a < FM; ++a)
        #pragma unroll
        for (int b = 0; b < 2; ++b) {
            acc1[a][b] = f32x4{0.f, 0.f, 0.f, 0.f};
            acc2[a][b] = f32x4{0.f, 0.f, 0.f, 0.f};
        }

    u16x8 pbaX[NB], pbaY[NB];
    f32x4 pbX[4], pbY[4];

    auto loadT = [&](int k0, u16x8 (&pba)[NB], f32x4 (&pb)[4]) {
        #pragma unroll
        for (int i = 0; i < NB; ++i)
            pba[i] = *(const u16x8*)(apb + k0 + i * 8);
        if (doB) {
            #pragma unroll
            for (int j = 0; j < 4; ++j) {
                const f32x4* src = (const f32x4*)(bp + (size_t)(k0 + j) * N);
                if (EXPERT) pb[j] = __builtin_nontemporal_load(src);
                else        pb[j] = *src;
            }
        }
    };

    auto storeT = [&](int p, u16x8 (&pba)[NB], f32x4 (&pb)[4]) {
        #pragma unroll
        for (int i = 0; i < NB; ++i)
            *(u16x8*)&lA[p][arow][akb + i * 8] = pba[i];
        if (doB) {
            #pragma unroll
            for (int j2 = 0; j2 < 4; ++j2) {
                u16x4 h = { f2bf(pb[0][j2]), f2bf(pb[1][j2]),
                            f2bf(pb[2][j2]), f2bf(pb[3][j2]) };
                *(u16x4*)&lB[p][bmat][nq * 4 + j2][kq * 4] = h;
            }
        }
    };

    auto compute = [&](int p) {
        const int koff = (lane >> 4) * 8;
        s16x8 af[FM], b1f[2], b2f[2];
        #pragma unroll
        for (int fm = 0; fm < FM; ++fm)
            af[fm] = *(const s16x8*)&lA[p][wm * WR + fm * 16 + (lane & 15)][koff];
        #pragma unroll
        for (int fn = 0; fn < 2; ++fn) {
            b1f[fn] = *(const s16x8*)&lB[p][0][wn * 32 + fn * 16 + (lane & 15)][koff];
            if (DUAL)
                b2f[fn] = *(const s16x8*)&lB[p][1][wn * 32 + fn * 16 + (lane & 15)][koff];
        }
        #pragma unroll
        for (int fm = 0; fm < FM; ++fm)
            #pragma unroll
            for (int fn = 0; fn < 2; ++fn) {
                acc1[fm][fn] = __builtin_amdgcn_mfma_f32_16x16x32_bf16(
                    af[fm], b1f[fn], acc1[fm][fn], 0, 0, 0);
                if (DUAL)
                    acc2[fm][fn] = __builtin_amdgcn_mfma_f32_16x16x32_bf16(
                        af[fm], b2f[fn], acc2[fm][fn], 0, 0, 0);
            }
    };

    const int nk = K >> 5;             // 32 or 64, even
    loadT(0, pbaX, pbX);
    loadT(32, pbaY, pbY);
    storeT(0, pbaX, pbX);
    __syncthreads();

    for (int kt = 0; kt < nk; kt += 2) {
        if (kt + 2 < nk) loadT((kt + 2) << 5, pbaX, pbX);
        compute(0);
        storeT(1, pbaY, pbY);          // counted vmcnt: newer loads in flight
        __syncthreads();
        if (kt + 3 < nk) loadT((kt + 3) << 5, pbaY, pbY);
        compute(1);
        if (kt + 2 < nk) {
            storeT(0, pbaX, pbX);
            __syncthreads();
        }
    }

    // ---- epilogue: bf16 store (SiLU fused for DUAL) ----
    const int fr = (lane >> 4) << 2;
    const int fc = lane & 15;
    #pragma unroll
    for (int fm = 0; fm < FM; ++fm)
        #pragma unroll
        for (int fn = 0; fn < 2; ++fn)
            #pragma unroll
            for (int j = 0; j < 4; ++j) {
                int r = wm * WR + fm * 16 + fr + j;
                if (row0 + r < Mloc) {
                    int cc = col0 + wn * 32 + fn * 16 + fc;
                    float v;
                    if (DUAL) {
                        float gv = acc1[fm][fn][j];
                        float uv = acc2[fm][fn][j];
                        v = gv / (1.f + expf(-gv)) * uv;
                    } else {
                        v = acc1[fm][fn][j];
                    }
                    outp[(size_t)(rb + row0 + r) * N + cc] = f2bf(v);
                }
            }
}

// ---------------------------------------------------------------------------
extern "C" void kernel_launch(void* const* d_in, const int* in_sizes, int n_in,
                              void* d_out, int out_size, void* d_ws, size_t ws_size,
                              hipStream_t stream) {
    const float* x       = (const float*)d_in[0];
    const float* gate_w  = (const float*)d_in[1];
    const float* bias    = (const float*)d_in[2];
    const float* w_gate  = (const float*)d_in[3];
    const float* w_up    = (const float*)d_in[4];
    const float* w_down  = (const float*)d_in[5];
    const float* sw_gate = (const float*)d_in[6];
    const float* sw_up   = (const float*)d_in[7];
    const float* sw_down = (const float*)d_in[8];
    float* out = (float*)d_out;

    char* ws = (char*)d_ws;
    int*   topk_idx = (int*)ws;                        // 32 KB
    float* topk_w   = (float*)(ws + 32768);            // 32 KB
    int*   counts   = (int*)(ws + 65536);              // 128 B
    int*   offsets  = (int*)(ws + 65664);              // 128 B
    int*   ppos     = (int*)(ws + 65792);              // 32 KB
    int*   ltok     = (int*)(ws + 98560);              // 128 KB
    unsigned short* xbf   = (unsigned short*)(ws + 262144);          // 4 MB
    unsigned short* act_s = xbf + (size_t)T_TOK * H_DIM;             // 4 MB
    unsigned short* shd   = act_s + (size_t)T_TOK * IS_DIM;          // 4 MB
    unsigned short* act_r = shd + (size_t)T_TOK * H_DIM;             // 16 MB
    unsigned short* yd    = act_r + (size_t)T_TOK * 8 * I_DIM;       // 32 MB

    cvt_k<<<T_TOK * H_DIM / 2048, 256, 0, stream>>>(x, xbf);
    route_k<<<T_TOK / 4, 256, 0, stream>>>(x, gate_w, bias, topk_idx, topk_w);
    build_k<<<E_NUM, 64, 0, stream>>>(topk_idx, ltok, ppos, counts);
    prefix_k<<<1, 64, 0, stream>>>(counts, offsets);

    // shared gate/up -> act_s (bf16, SiLU fused): BM=128
    gemm_k<1,0,0,128><<<dim3(8, 32, 1), 512, 0, stream>>>(
        xbf, sw_gate, sw_up, act_s, nullptr, nullptr, nullptr,
        T_TOK, IS_DIM, H_DIM);
    // routed gate/up -> act_r (bf16, SiLU fused): BM=256, gathered A
    gemm_k<1,1,1,256><<<dim3(4, 16, 32), 512, 0, stream>>>(
        xbf, w_gate, w_up, act_r, counts, offsets, ltok,
        T_TOK, I_DIM, H_DIM);
    // shared down -> shd (bf16): BM=128
    gemm_k<0,0,0,128><<<dim3(8, 32, 1), 512, 0, stream>>>(
        act_s, sw_down, nullptr, shd, nullptr, nullptr, nullptr,
        T_TOK, H_DIM, IS_DIM);
    // routed down -> yd rows (bf16, no atomics): BM=256
    gemm_k<0,1,0,256><<<dim3(4, 32, 32), 512, 0, stream>>>(
        act_r, w_down, nullptr, yd, counts, offsets, ltok,
        T_TOK, H_DIM, I_DIM);

    // out[t] = shd[t] + sum_k w_k * yd[row_k]
    combine_k<<<T_TOK, 256, 0, stream>>>(
        topk_idx, topk_w, offsets, ppos, shd, yd, out);
}